// Round 5
// baseline (382.262 us; speedup 1.0000x reference)
//
#include <hip/hip_runtime.h>

// Integrator: y = cumsum(x, axis=-1) over (8,4,1048576) fp32.
// Two-kernel reduce-then-scan (proven best structure; in-kernel cross-block
// sync costs 100+ us on the 8-XCD coherence fabric — rounds 1-2):
//   A: per-tile sums (read x once from HBM, coalesced float4, 4 accumulators)
//   B: redundant per-wave reduce of <=255 predecessor tile sums (part[] is
//      32 KB, L2-hot), 16-elem/thread local scan, wave+block scan, add offset,
//      nontemporal y stores (y never re-read; keeps x L3-resident so B's
//      x re-read stays an Infinity-Cache hit even as y writes stream out).
// HBM floor: 134 MB read + 134 MB write.

typedef float vf4 __attribute__((ext_vector_type(4)));  // native vec for nt-store

constexpr int ROWS           = 32;        // B*C = 8*4
constexpr int T_LEN          = 1048576;
constexpr int THREADS        = 256;
constexpr int PER_THREAD     = 16;        // contiguous floats per thread in B
constexpr int TILE           = THREADS * PER_THREAD;   // 4096
constexpr int BLOCKS_PER_ROW = T_LEN / TILE;           // 256
constexpr int TOTAL_BLOCKS   = ROWS * BLOCKS_PER_ROW;  // 8192

// ---------------- A: per-tile sums ----------------
__global__ __launch_bounds__(THREADS) void integ_reduce(
    const float* __restrict__ x, float* __restrict__ part) {
  const int blk = blockIdx.x;
  const size_t base = (size_t)blk * TILE;
  const float4* p = (const float4*)(x + base);
  const int t = threadIdx.x;
  const int lane = t & 63;
  const int wid  = t >> 6;

  // 4 dense float4 sweeps, independent accumulators (no serial FMA chain)
  float4 a = p[0 * THREADS + t];
  float4 b = p[1 * THREADS + t];
  float4 c = p[2 * THREADS + t];
  float4 d = p[3 * THREADS + t];
  float s0 = (a.x + a.y) + (a.z + a.w);
  float s1 = (b.x + b.y) + (b.z + b.w);
  float s2 = (c.x + c.y) + (c.z + c.w);
  float s3 = (d.x + d.y) + (d.z + d.w);
  float s = (s0 + s1) + (s2 + s3);
#pragma unroll
  for (int o = 32; o > 0; o >>= 1) s += __shfl_down(s, o, 64);

  __shared__ float wsum[4];
  if (lane == 0) wsum[wid] = s;
  __syncthreads();
  if (t == 0) part[blk] = (wsum[0] + wsum[1]) + (wsum[2] + wsum[3]);
}

// ---------------- B: offset + local scan + write ----------------
__global__ __launch_bounds__(THREADS) void integ_scan(
    const float* __restrict__ x, float* __restrict__ y,
    const float* __restrict__ part) {
  const int blk = blockIdx.x;
  const int row = blk >> 8;                // / BLOCKS_PER_ROW
  const int tb  = blk & (BLOCKS_PER_ROW - 1);
  const int t = threadIdx.x;
  const int lane = t & 63;
  const int wid  = t >> 6;

  __shared__ float s_pred[4];    // per-wave predecessor partial sums
  __shared__ float s_wscan[4];   // per-wave scan totals

  // 1) predecessor tile-sum: thread t owns part[row*256 + t] if t < tb
  float ps = (t < tb) ? part[(row << 8) + t] : 0.f;
#pragma unroll
  for (int o = 32; o > 0; o >>= 1) ps += __shfl_xor(ps, o, 64);
  if (lane == 0) s_pred[wid] = ps;

  // 2) load tile: 16 contiguous floats per thread (issues early, long latency)
  const size_t base = (size_t)blk * TILE + (size_t)t * PER_THREAD;
  const float4* p = (const float4*)(x + base);
  float v[PER_THREAD];
#pragma unroll
  for (int j = 0; j < PER_THREAD / 4; ++j) {
    float4 q = p[j];
    v[4 * j + 0] = q.x; v[4 * j + 1] = q.y; v[4 * j + 2] = q.z; v[4 * j + 3] = q.w;
  }

  // 3) thread-local inclusive scan
#pragma unroll
  for (int i = 1; i < PER_THREAD; ++i) v[i] += v[i - 1];
  const float tsum = v[PER_THREAD - 1];

  // 4) block scan of per-thread sums
  float s = tsum;
#pragma unroll
  for (int d = 1; d < 64; d <<= 1) {
    float n = __shfl_up(s, d, 64);
    if (lane >= d) s += n;
  }
  if (lane == 63) s_wscan[wid] = s;
  __syncthreads();   // single barrier: covers s_pred and s_wscan

  float off = (s_pred[0] + s_pred[1]) + (s_pred[2] + s_pred[3]);
  float prev = 0.f;
#pragma unroll
  for (int w = 0; w < 4; ++w) prev += (w < wid) ? s_wscan[w] : 0.f;
  off += prev + s - tsum;        // + exclusive prefix within tile

#pragma unroll
  for (int i = 0; i < PER_THREAD; ++i) v[i] += off;

  // 5) nontemporal streaming stores: y is never re-read; don't evict x from L3
  vf4* q = (vf4*)(y + base);
#pragma unroll
  for (int j = 0; j < PER_THREAD / 4; ++j) {
    vf4 o;
    o.x = v[4 * j + 0]; o.y = v[4 * j + 1];
    o.z = v[4 * j + 2]; o.w = v[4 * j + 3];
    __builtin_nontemporal_store(o, q + j);
  }
}

extern "C" void kernel_launch(void* const* d_in, const int* in_sizes, int n_in,
                              void* d_out, int out_size, void* d_ws, size_t ws_size,
                              hipStream_t stream) {
  const float* x = (const float*)d_in[0];
  float* y = (float*)d_out;
  float* part = (float*)d_ws;   // TOTAL_BLOCKS floats = 32 KB

  integ_reduce<<<TOTAL_BLOCKS, THREADS, 0, stream>>>(x, part);
  integ_scan  <<<TOTAL_BLOCKS, THREADS, 0, stream>>>(x, y, part);
}

// Round 6
// 252.320 us; speedup vs baseline: 1.5150x; 1.5150x over previous
//
#include <hip/hip_runtime.h>

// Integrator: y = cumsum(x, axis=-1) over (8,4,1048576) fp32.
// Two-kernel reduce-then-scan — the measured-optimal structure (R0=252.7us).
// Ledger: decoupled lookback +955us (cross-block spin on 8-XCD coherence
// fabric); cooperative grid.sync +120us; 8192-float tiles +5us; nontemporal
// stores +130us (nt bypasses L2 write-combining -> 2.5x WRITE_SIZE).
//   A: per-tile sums (read x once, coalesced float4, independent accumulators)
//   B: wave-parallel reduce of <=255 predecessor tile sums (part[] 32 KB,
//      L2-hot), 16-elem/thread local scan, wave+block scan, add offset,
//      plain cached float4 stores (L2 write-combines to full lines).
// HBM floor: 134 MB read + 134 MB write; B's x re-read is L3-resident.

constexpr int ROWS           = 32;        // B*C = 8*4
constexpr int T_LEN          = 1048576;
constexpr int THREADS        = 256;
constexpr int PER_THREAD     = 16;        // contiguous floats per thread in B
constexpr int TILE           = THREADS * PER_THREAD;   // 4096
constexpr int BLOCKS_PER_ROW = T_LEN / TILE;           // 256
constexpr int TOTAL_BLOCKS   = ROWS * BLOCKS_PER_ROW;  // 8192

// ---------------- A: per-tile sums ----------------
__global__ __launch_bounds__(THREADS) void integ_reduce(
    const float* __restrict__ x, float* __restrict__ part) {
  const int blk = blockIdx.x;
  const size_t base = (size_t)blk * TILE;
  const float4* p = (const float4*)(x + base);
  const int t = threadIdx.x;
  const int lane = t & 63;
  const int wid  = t >> 6;

  // 4 dense float4 sweeps, independent accumulators (no serial FMA chain)
  float4 a = p[0 * THREADS + t];
  float4 b = p[1 * THREADS + t];
  float4 c = p[2 * THREADS + t];
  float4 d = p[3 * THREADS + t];
  float s0 = (a.x + a.y) + (a.z + a.w);
  float s1 = (b.x + b.y) + (b.z + b.w);
  float s2 = (c.x + c.y) + (c.z + c.w);
  float s3 = (d.x + d.y) + (d.z + d.w);
  float s = (s0 + s1) + (s2 + s3);
#pragma unroll
  for (int o = 32; o > 0; o >>= 1) s += __shfl_down(s, o, 64);

  __shared__ float wsum[4];
  if (lane == 0) wsum[wid] = s;
  __syncthreads();
  if (t == 0) part[blk] = (wsum[0] + wsum[1]) + (wsum[2] + wsum[3]);
}

// ---------------- B: offset + local scan + write ----------------
__global__ __launch_bounds__(THREADS) void integ_scan(
    const float* __restrict__ x, float* __restrict__ y,
    const float* __restrict__ part) {
  const int blk = blockIdx.x;
  const int row = blk >> 8;                // / BLOCKS_PER_ROW
  const int tb  = blk & (BLOCKS_PER_ROW - 1);
  const int t = threadIdx.x;
  const int lane = t & 63;
  const int wid  = t >> 6;

  __shared__ float s_pred[4];    // per-wave predecessor partial sums
  __shared__ float s_wscan[4];   // per-wave scan totals

  // 1) predecessor tile-sum: thread t owns part[row*256 + t] if t < tb
  float ps = (t < tb) ? part[(row << 8) + t] : 0.f;
#pragma unroll
  for (int o = 32; o > 0; o >>= 1) ps += __shfl_xor(ps, o, 64);
  if (lane == 0) s_pred[wid] = ps;

  // 2) load tile: 16 contiguous floats per thread (issues early, long latency)
  const size_t base = (size_t)blk * TILE + (size_t)t * PER_THREAD;
  const float4* p = (const float4*)(x + base);
  float v[PER_THREAD];
#pragma unroll
  for (int j = 0; j < PER_THREAD / 4; ++j) {
    float4 q = p[j];
    v[4 * j + 0] = q.x; v[4 * j + 1] = q.y; v[4 * j + 2] = q.z; v[4 * j + 3] = q.w;
  }

  // 3) thread-local inclusive scan
#pragma unroll
  for (int i = 1; i < PER_THREAD; ++i) v[i] += v[i - 1];
  const float tsum = v[PER_THREAD - 1];

  // 4) block scan of per-thread sums
  float s = tsum;
#pragma unroll
  for (int d = 1; d < 64; d <<= 1) {
    float n = __shfl_up(s, d, 64);
    if (lane >= d) s += n;
  }
  if (lane == 63) s_wscan[wid] = s;
  __syncthreads();   // single barrier: covers s_pred and s_wscan

  float off = (s_pred[0] + s_pred[1]) + (s_pred[2] + s_pred[3]);
  float prev = 0.f;
#pragma unroll
  for (int w = 0; w < 4; ++w) prev += (w < wid) ? s_wscan[w] : 0.f;
  off += prev + s - tsum;        // + exclusive prefix within tile

#pragma unroll
  for (int i = 0; i < PER_THREAD; ++i) v[i] += off;

  // 5) plain cached stores — L2 write-combines adjacent lanes into full lines
  float4* q = (float4*)(y + base);
#pragma unroll
  for (int j = 0; j < PER_THREAD / 4; ++j) {
    float4 o;
    o.x = v[4 * j + 0]; o.y = v[4 * j + 1];
    o.z = v[4 * j + 2]; o.w = v[4 * j + 3];
    q[j] = o;
  }
}

extern "C" void kernel_launch(void* const* d_in, const int* in_sizes, int n_in,
                              void* d_out, int out_size, void* d_ws, size_t ws_size,
                              hipStream_t stream) {
  const float* x = (const float*)d_in[0];
  float* y = (float*)d_out;
  float* part = (float*)d_ws;   // TOTAL_BLOCKS floats = 32 KB

  integ_reduce<<<TOTAL_BLOCKS, THREADS, 0, stream>>>(x, part);
  integ_scan  <<<TOTAL_BLOCKS, THREADS, 0, stream>>>(x, y, part);
}